// Round 1
// baseline (466.708 us; speedup 1.0000x reference)
//
#include <hip/hip_runtime.h>
#include <math.h>

#define N_ 4096
#define D_ 64
#define NC_ 1000
#define KQ_ 8192
#define TEMP_INV 20.0f
#define VCOLS (NC_ + KQ_)   // 9192 matmul columns (centers + queue)

// workspace layout (float offsets)
#define WS_F    0
#define WS_CENT (WS_F + N_*D_)        // 262144
#define WS_MU   (WS_CENT + NC_*D_)    // +64000
#define WS_CNT  (WS_MU + D_)
#define WS_ACC  (WS_CNT + NC_)
#define A_CENUM 0
#define A_CEDEN 1
#define A_CSUM  2
#define A_ISUM  3
#define A_SW    4
#define A_SB    5
#define A_IMIN  6

__global__ __launch_bounds__(256) void k_init(float* ws) {
    int t = blockIdx.x * 256 + threadIdx.x;
    if (t < NC_) ws[WS_CNT + t] = 0.0f;
    if (t < D_)  ws[WS_MU + t] = 0.0f;
    if (t < 8)   ws[WS_ACC + t] = 0.0f;
    if (t == 0)  ((unsigned*)ws)[WS_ACC + A_IMIN] = 0x7F800000u; // +inf
}

// normalize feats rows: one wave per row
__global__ __launch_bounds__(256) void k_norm_f(const float* __restrict__ feats,
                                                float* __restrict__ f) {
    int row  = blockIdx.x * 4 + (threadIdx.x >> 6);
    int lane = threadIdx.x & 63;
    float x = feats[row * D_ + lane];
    float ss = x * x;
    #pragma unroll
    for (int m = 32; m >= 1; m >>= 1) ss += __shfl_xor(ss, m, 64);
    float n = fmaxf(sqrtf(ss), 1e-12f);
    f[row * D_ + lane] = x / n;
}

// normalize C columns -> centers [NC, D] row-major; one thread per column
__global__ __launch_bounds__(256) void k_norm_c(const float* __restrict__ C,
                                                float* __restrict__ cent) {
    int c = blockIdx.x * 256 + threadIdx.x;
    if (c >= NC_) return;
    float v[D_];
    float ss = 0.0f;
    #pragma unroll
    for (int d = 0; d < D_; ++d) { float x = C[d * NC_ + c]; v[d] = x; ss += x * x; }
    float n = fmaxf(sqrtf(ss), 1e-12f);
    float inv = 1.0f / n;
    #pragma unroll
    for (int d = 0; d < D_; ++d) cent[c * D_ + d] = v[d] * inv;
}

// mu_sum, cls_cnt, S_W : one wave handles strided rows
__global__ __launch_bounds__(256) void k_stats(const float* __restrict__ f,
                                               const float* __restrict__ cent,
                                               const int* __restrict__ labels,
                                               float* ws) {
    int wid  = blockIdx.x * 4 + (threadIdx.x >> 6); // 0..255
    int lane = threadIdx.x & 63;
    float mu = 0.0f, sw = 0.0f;
    for (int i = wid; i < N_; i += 256) {
        int l = labels[i];
        float x = f[i * D_ + lane];
        mu += x;
        float dv = x - cent[l * D_ + lane];
        sw += dv * dv;
        if (lane == 0) atomicAdd(&ws[WS_CNT + l], 1.0f);
    }
    #pragma unroll
    for (int m = 32; m >= 1; m >>= 1) sw += __shfl_xor(sw, m, 64);
    if (lane == 0) atomicAdd(&ws[WS_ACC + A_SW], sw);
    atomicAdd(&ws[WS_MU + lane], mu);
}

// S_B = sum_c ||centers[c]-mu||^2 * cnt[c]
__global__ __launch_bounds__(256) void k_sb(const float* __restrict__ cent, float* ws) {
    int c = blockIdx.x * 256 + threadIdx.x;
    if (c >= NC_) return;
    float cnt = ws[WS_CNT + c];
    float s = 0.0f;
    const float invN = 1.0f / (float)N_;
    #pragma unroll
    for (int d = 0; d < D_; ++d) {
        float dv = cent[c * D_ + d] - ws[WS_MU + d] * invN;
        s += dv * dv;
    }
    atomicAdd(&ws[WS_ACC + A_SB], s * cnt);
}

// gram -> inter_min, inter_sum (off-diag)
__global__ __launch_bounds__(256) void k_gram(const float* __restrict__ cent, float* ws) {
    __shared__ float A[64 * 68];
    __shared__ float B[64 * 68];
    int bx = blockIdx.x & 15, by = blockIdx.x >> 4;
    int i0 = bx * 64, j0 = by * 64;
    int t = threadIdx.x;
    for (int q = t; q < 64 * 16; q += 256) {
        int r = q >> 4, dv = q & 15;
        float4 a = make_float4(0, 0, 0, 0), b = make_float4(0, 0, 0, 0);
        if (i0 + r < NC_) a = ((const float4*)(cent + (i0 + r) * D_))[dv];
        if (j0 + r < NC_) b = ((const float4*)(cent + (j0 + r) * D_))[dv];
        *(float4*)(A + r * 68 + dv * 4) = a;
        *(float4*)(B + r * 68 + dv * 4) = b;
    }
    __syncthreads();
    int ti = t >> 4, tj = t & 15;
    float lsum = 0.0f, lmin = 1e30f;
    #pragma unroll
    for (int a = 0; a < 4; ++a) {
        #pragma unroll
        for (int b = 0; b < 4; ++b) {
            int il = ti + 16 * a, jl = tj + 16 * b;
            int gi = i0 + il, gj = j0 + jl;
            if (gi < NC_ && gj < NC_ && gi != gj) {
                float acc = 0.0f;
                #pragma unroll
                for (int k = 0; k < D_; ++k) acc += A[il * 68 + k] * B[jl * 68 + k];
                float sq = fmaxf(2.0f - 2.0f * acc, 1e-12f);
                float d = sqrtf(sq);
                lsum += d;
                lmin = fminf(lmin, d);
            }
        }
    }
    #pragma unroll
    for (int m = 32; m >= 1; m >>= 1) {
        lsum += __shfl_xor(lsum, m, 64);
        lmin = fminf(lmin, __shfl_xor(lmin, m, 64));
    }
    __shared__ float wsum[4], wmin[4];
    int wv = t >> 6;
    if ((t & 63) == 0) { wsum[wv] = lsum; wmin[wv] = lmin; }
    __syncthreads();
    if (t == 0) {
        float S = wsum[0] + wsum[1] + wsum[2] + wsum[3];
        float Mn = fminf(fminf(wmin[0], wmin[1]), fminf(wmin[2], wmin[3]));
        atomicAdd(&ws[WS_ACC + A_ISUM], S);
        atomicMin((unsigned int*)&ws[WS_ACC + A_IMIN], __float_as_uint(Mn));
    }
}

// fused CE + contrastive row-softmax.
// grid: N/16 blocks of 256 threads; thread (tr=t/16 row, tc=t%16 col-lane)
#define CHUNK 128
#define CPAD 68
__global__ __launch_bounds__(256) void k_main(const float* __restrict__ logits,
                                              const int* __restrict__ labels,
                                              const float* __restrict__ log_prior,
                                              const float* __restrict__ class_weight,
                                              const float* __restrict__ f,
                                              const float* __restrict__ cent,
                                              const float* __restrict__ queue,
                                              float* ws) {
    __shared__ float chunk[CHUNK * CPAD];
    __shared__ float pos_cent[16];
    int t = threadIdx.x;
    int tr = t >> 4, tc = t & 15;
    int i = blockIdx.x * 16 + tr;
    int l = labels[i];

    // f row into registers
    float4 fr[16];
    const float4* frow = (const float4*)(f + i * D_);
    #pragma unroll
    for (int d = 0; d < 16; ++d) fr[d] = frow[d];

    float mce = -__builtin_inff(), sce = 0.0f;  // CE online (scale 1)
    float m   = -__builtin_inff(), s   = 0.0f;  // contrast online (scale 20)

    // phase A: sup block (read logits)
    const float* lrow = logits + (size_t)i * NC_;
    for (int c = tc; c < NC_; c += 16) {
        float v = lrow[c] + log_prior[c];
        if (v <= mce) { sce += __expf(v - mce); }
        else { sce = sce * __expf(mce - v) + 1.0f; mce = v; }
        float a = v * TEMP_INV;
        if (a <= m) { s += __expf(a - m); }
        else { s = s * __expf(m - a) + 1.0f; m = a; }
    }

    // phase B: tiled pass over 9192 virtual columns
    for (int base = 0; base < VCOLS; base += CHUNK) {
        __syncthreads();
        for (int q = t; q < CHUNK * 16; q += 256) {
            int c = q >> 4, dv = q & 15;
            int j = base + c;
            float4 val = make_float4(0, 0, 0, 0);
            if (j < VCOLS) {
                const float* src = (j < NC_) ? (cent + j * D_)
                                 : (j < NC_ + N_) ? (f + (j - NC_) * D_)
                                 : (queue + (size_t)(j - NC_) * D_);
                val = ((const float4*)src)[dv];
            }
            *(float4*)(chunk + c * CPAD + dv * 4) = val;
        }
        __syncthreads();
        #pragma unroll
        for (int cc = 0; cc < 8; ++cc) {
            int cl = tc + 16 * cc;
            int j = base + cl;
            if (j >= VCOLS) continue;
            const float* b = chunk + cl * CPAD;
            float acc = 0.0f;
            #pragma unroll
            for (int dv = 0; dv < 16; ++dv) {
                float4 b4 = *(const float4*)(b + dv * 4);
                acc += fr[dv].x * b4.x + fr[dv].y * b4.y
                     + fr[dv].z * b4.z + fr[dv].w * b4.w;
            }
            if (j < NC_ && j == l) pos_cent[tr] = acc;
            float a = acc * TEMP_INV;
            if (a <= m) { s += __expf(a - m); }
            else { s = s * __expf(m - a) + 1.0f; m = a; }
        }
    }
    __syncthreads();

    // phase C: merge (m,s) across 16 col-lanes
    #pragma unroll
    for (int k = 1; k < 16; k <<= 1) {
        float om = __shfl_xor(m, k, 64);
        float os = __shfl_xor(s, k, 64);
        float M = fmaxf(m, om);
        s = s * __expf(m - M) + os * __expf(om - M);
        m = M;
        float omc = __shfl_xor(mce, k, 64);
        float osc = __shfl_xor(sce, k, 64);
        float Mc = fmaxf(mce, omc);
        sce = sce * __expf(mce - Mc) + osc * __expf(omc - Mc);
        mce = Mc;
    }
    if (tc == 0) {
        float vpos = lrow[l] + log_prior[l];
        float w = class_weight[l];
        float nll = (mce + __logf(sce)) - vpos;
        atomicAdd(&ws[WS_ACC + A_CENUM], w * nll);
        atomicAdd(&ws[WS_ACC + A_CEDEN], w);
        float lse = __logf(s + 1e-12f);
        float lp1 = vpos * TEMP_INV - m - lse;
        float lp2 = pos_cent[tr] * TEMP_INV - m - lse;
        float mlpp = (1.0f * lp1 + 0.02f * lp2) / (1.02f + 1e-12f);
        atomicAdd(&ws[WS_ACC + A_CSUM], mlpp);
    }
}

__global__ void k_final(const float* __restrict__ ws, float* __restrict__ out) {
    float ce = ws[WS_ACC + A_CENUM] / ws[WS_ACC + A_CEDEN];
    float contrast = -(ws[WS_ACC + A_CSUM] / (float)N_);
    float inter_mean = ws[WS_ACC + A_ISUM] / (float)(NC_ * (NC_ - 1));
    float inter_min = __uint_as_float(((const unsigned*)ws)[WS_ACC + A_IMIN]);
    float sw = ws[WS_ACC + A_SW];
    float sb = ws[WS_ACC + A_SB];
    float intra = sw / (float)N_;
    float fisher = sb / (sw + 1e-6f);
    float reg = 1.0f * intra + 0.1f / (inter_mean + 1e-6f)
              + 0.05f / (inter_min + 1e-6f) + 0.1f / (fisher + 1e-6f);
    out[0] = ce + contrast + reg;
}

extern "C" void kernel_launch(void* const* d_in, const int* in_sizes, int n_in,
                              void* d_out, int out_size, void* d_ws, size_t ws_size,
                              hipStream_t stream) {
    const float* feats        = (const float*)d_in[0];
    const float* logits       = (const float*)d_in[1];
    const int*   labels       = (const int*)d_in[2];
    const float* C            = (const float*)d_in[3];
    const float* queue        = (const float*)d_in[4];
    const float* log_prior    = (const float*)d_in[5];
    const float* class_weight = (const float*)d_in[6];
    float* ws  = (float*)d_ws;
    float* out = (float*)d_out;

    hipLaunchKernelGGL(k_init,   dim3(4),      dim3(256), 0, stream, ws);
    hipLaunchKernelGGL(k_norm_f, dim3(N_ / 4), dim3(256), 0, stream, feats, ws + WS_F);
    hipLaunchKernelGGL(k_norm_c, dim3(4),      dim3(256), 0, stream, C, ws + WS_CENT);
    hipLaunchKernelGGL(k_stats,  dim3(64),     dim3(256), 0, stream,
                       ws + WS_F, ws + WS_CENT, labels, ws);
    hipLaunchKernelGGL(k_sb,     dim3(4),      dim3(256), 0, stream, ws + WS_CENT, ws);
    hipLaunchKernelGGL(k_gram,   dim3(256),    dim3(256), 0, stream, ws + WS_CENT, ws);
    hipLaunchKernelGGL(k_main,   dim3(N_ / 16), dim3(256), 0, stream,
                       logits, labels, log_prior, class_weight,
                       ws + WS_F, ws + WS_CENT, queue, ws);
    hipLaunchKernelGGL(k_final,  dim3(1),      dim3(1),   0, stream, ws, out);
}

// Round 2
// 250.264 us; speedup vs baseline: 1.8649x; 1.8649x over previous
//
#include <hip/hip_runtime.h>
#include <math.h>

#define N_ 4096
#define D_ 64
#define NC_ 1000
#define KQ_ 8192
#define VCOLS 9192          // NC + KQ real columns
#define VPAD  9216          // 72*128 padded
#define NCB   72
#define PCH   73            // 72 gemm chunks + 1 sup chunk
#define TEMP_INV 20.0f

// workspace layout (float offsets)
#define WS_F     0
#define WS_CENT  (WS_F + N_*D_)
#define WS_MU    (WS_CENT + NC_*D_)
#define WS_CNT   (WS_MU + D_)
#define WS_ACC   (WS_CNT + NC_)
#define WS_PM    (WS_ACC + 16)
#define WS_PS    (WS_PM + N_*PCH)
#define WS_PCENT (WS_PS + N_*PCH)
#define WS_PSUP  (WS_PCENT + N_)
#define WS_BBF   (WS_PSUP + N_)           // ushort[VPAD*64] lives here
#define A_CENUM 0
#define A_CEDEN 1
#define A_CSUM  2
#define A_ISUM  3
#define A_SW    4
#define A_SB    5
#define A_IMIN  6

typedef __attribute__((ext_vector_type(8))) short short8_t;
typedef __attribute__((ext_vector_type(4))) float f32x4;

__device__ __forceinline__ ushort f2bf(float x) {
    union { float f; unsigned u; } v; v.f = x;
    unsigned r = (v.u + 0x7FFFu + ((v.u >> 16) & 1u)) >> 16;
    return (ushort)r;
}

__global__ __launch_bounds__(256) void k_init(float* ws) {
    int t = blockIdx.x * 256 + threadIdx.x;
    if (t < NC_) ws[WS_CNT + t] = 0.0f;
    if (t < D_)  ws[WS_MU + t] = 0.0f;
    if (t < 8)   ws[WS_ACC + t] = 0.0f;
    if (t == 0)  ((unsigned*)ws)[WS_ACC + A_IMIN] = 0x7F800000u; // +inf
}

// normalize feats rows -> f fp32, and bf16 into B rows [NC_ .. NC_+N_)
__global__ __launch_bounds__(256) void k_norm_f(const float* __restrict__ feats,
                                                float* __restrict__ f,
                                                ushort* __restrict__ B) {
    int row  = blockIdx.x * 4 + (threadIdx.x >> 6);
    int lane = threadIdx.x & 63;
    float x = feats[row * D_ + lane];
    float ss = x * x;
    #pragma unroll
    for (int m = 32; m >= 1; m >>= 1) ss += __shfl_xor(ss, m, 64);
    float n = fmaxf(sqrtf(ss), 1e-12f);
    float y = x / n;
    f[row * D_ + lane] = y;
    B[(size_t)(NC_ + row) * D_ + lane] = f2bf(y);
}

// normalize C columns -> centers fp32 [NC][D] + bf16 into B rows [0..NC_)
__global__ __launch_bounds__(256) void k_norm_c(const float* __restrict__ C,
                                                float* __restrict__ cent,
                                                ushort* __restrict__ B) {
    int c = blockIdx.x * 256 + threadIdx.x;
    if (c >= NC_) return;
    float v[D_];
    float ss = 0.0f;
    #pragma unroll
    for (int d = 0; d < D_; ++d) { float x = C[d * NC_ + c]; v[d] = x; ss += x * x; }
    float inv = 1.0f / fmaxf(sqrtf(ss), 1e-12f);
    #pragma unroll
    for (int d = 0; d < D_; ++d) {
        float y = v[d] * inv;
        cent[c * D_ + d] = y;
        B[(size_t)c * D_ + d] = f2bf(y);
    }
}

// queue tail rows -> bf16 B rows [NC_+N_ .. NC_+KQ_), pad rows zeroed
__global__ __launch_bounds__(256) void k_qbf(const float* __restrict__ queue,
                                             ushort* __restrict__ B) {
    int t = blockIdx.x * 256 + threadIdx.x;           // over (4096+24)*64
    if (t >= (KQ_ - N_ + 24) * D_) return;
    int r = t >> 6, d = t & 63;
    ushort o = 0;
    if (r < KQ_ - N_) o = f2bf(queue[(size_t)(N_ + r) * D_ + d]);
    B[(size_t)(NC_ + N_ + r) * D_ + d] = o;
}

// mu_sum, cls_cnt, S_W
__global__ __launch_bounds__(256) void k_stats(const float* __restrict__ f,
                                               const float* __restrict__ cent,
                                               const int* __restrict__ labels,
                                               float* ws) {
    int wid  = blockIdx.x * 4 + (threadIdx.x >> 6);
    int lane = threadIdx.x & 63;
    float mu = 0.0f, sw = 0.0f;
    for (int i = wid; i < N_; i += 256) {
        int l = labels[i];
        float x = f[i * D_ + lane];
        mu += x;
        float dv = x - cent[l * D_ + lane];
        sw += dv * dv;
        if (lane == 0) atomicAdd(&ws[WS_CNT + l], 1.0f);
    }
    #pragma unroll
    for (int m = 32; m >= 1; m >>= 1) sw += __shfl_xor(sw, m, 64);
    if (lane == 0) atomicAdd(&ws[WS_ACC + A_SW], sw);
    atomicAdd(&ws[WS_MU + lane], mu);
}

__global__ __launch_bounds__(256) void k_sb(const float* __restrict__ cent, float* ws) {
    int c = blockIdx.x * 256 + threadIdx.x;
    if (c >= NC_) return;
    float cnt = ws[WS_CNT + c];
    float s = 0.0f;
    const float invN = 1.0f / (float)N_;
    #pragma unroll
    for (int d = 0; d < D_; ++d) {
        float dv = cent[c * D_ + d] - ws[WS_MU + d] * invN;
        s += dv * dv;
    }
    atomicAdd(&ws[WS_ACC + A_SB], s * cnt);
}

__global__ __launch_bounds__(256) void k_gram(const float* __restrict__ cent, float* ws) {
    __shared__ float A[64 * 68];
    __shared__ float Bs[64 * 68];
    int bx = blockIdx.x & 15, by = blockIdx.x >> 4;
    int i0 = bx * 64, j0 = by * 64;
    int t = threadIdx.x;
    for (int q = t; q < 64 * 16; q += 256) {
        int r = q >> 4, dv = q & 15;
        float4 a = make_float4(0, 0, 0, 0), b = make_float4(0, 0, 0, 0);
        if (i0 + r < NC_) a = ((const float4*)(cent + (i0 + r) * D_))[dv];
        if (j0 + r < NC_) b = ((const float4*)(cent + (j0 + r) * D_))[dv];
        *(float4*)(A + r * 68 + dv * 4) = a;
        *(float4*)(Bs + r * 68 + dv * 4) = b;
    }
    __syncthreads();
    int ti = t >> 4, tj = t & 15;
    float lsum = 0.0f, lmin = 1e30f;
    #pragma unroll
    for (int a = 0; a < 4; ++a)
        #pragma unroll
        for (int b = 0; b < 4; ++b) {
            int il = ti + 16 * a, jl = tj + 16 * b;
            int gi = i0 + il, gj = j0 + jl;
            if (gi < NC_ && gj < NC_ && gi != gj) {
                float acc = 0.0f;
                #pragma unroll
                for (int k = 0; k < D_; ++k) acc += A[il * 68 + k] * Bs[jl * 68 + k];
                float sq = fmaxf(2.0f - 2.0f * acc, 1e-12f);
                float d = sqrtf(sq);
                lsum += d;
                lmin = fminf(lmin, d);
            }
        }
    #pragma unroll
    for (int m = 32; m >= 1; m >>= 1) {
        lsum += __shfl_xor(lsum, m, 64);
        lmin = fminf(lmin, __shfl_xor(lmin, m, 64));
    }
    __shared__ float wsum[4], wmin[4];
    int wv = t >> 6;
    if ((t & 63) == 0) { wsum[wv] = lsum; wmin[wv] = lmin; }
    __syncthreads();
    if (t == 0) {
        float S = wsum[0] + wsum[1] + wsum[2] + wsum[3];
        float Mn = fminf(fminf(wmin[0], wmin[1]), fminf(wmin[2], wmin[3]));
        atomicAdd(&ws[WS_ACC + A_ISUM], S);
        atomicMin((unsigned int*)&ws[WS_ACC + A_IMIN], __float_as_uint(Mn));
    }
}

// CE + sup-block contrast partial: one wave per row over 1000 logits
__global__ __launch_bounds__(256) void k_sup(const float* __restrict__ logits,
                                             const int* __restrict__ labels,
                                             const float* __restrict__ log_prior,
                                             const float* __restrict__ class_weight,
                                             float* ws) {
    int w = threadIdx.x >> 6, l = threadIdx.x & 63;
    int row = blockIdx.x * 4 + w;
    const float* lrow = logits + (size_t)row * NC_;
    float v[16];
    #pragma unroll
    for (int it = 0; it < 16; ++it) {
        int col = l + it * 64;
        v[it] = (col < NC_) ? lrow[col] + log_prior[col] : -INFINITY;
    }
    float m = v[0];
    #pragma unroll
    for (int it = 1; it < 16; ++it) m = fmaxf(m, v[it]);
    #pragma unroll
    for (int msk = 1; msk < 64; msk <<= 1) m = fmaxf(m, __shfl_xor(m, msk, 64));
    float s1 = 0.0f, s20 = 0.0f;
    #pragma unroll
    for (int it = 0; it < 16; ++it) {
        float d = v[it] - m;
        s1  += __expf(d);
        s20 += __expf(TEMP_INV * d);
    }
    #pragma unroll
    for (int msk = 1; msk < 64; msk <<= 1) {
        s1  += __shfl_xor(s1, msk, 64);
        s20 += __shfl_xor(s20, msk, 64);
    }
    if (l == 0) {
        int lab = labels[row];
        float vpos = lrow[lab] + log_prior[lab];
        float wt = class_weight[lab];
        atomicAdd(&ws[WS_ACC + A_CENUM], wt * (m + __logf(s1) - vpos));
        atomicAdd(&ws[WS_ACC + A_CEDEN], wt);
        ws[WS_PM + (size_t)row * PCH + (PCH - 1)] = TEMP_INV * m;
        ws[WS_PS + (size_t)row * PCH + (PCH - 1)] = s20;
        ws[WS_PSUP + row] = TEMP_INV * vpos;
    }
}

// MFMA GEMM f @ B^T fused with per-chunk (max, sumexp) reduction.
// grid (64, 72); block 256 = 4 waves in 2x2; wave tile 32 rows x 64 cols.
__global__ __launch_bounds__(256) void k_gemm(const ushort* __restrict__ B,
                                              const int* __restrict__ labels,
                                              float* __restrict__ ws) {
    int l = threadIdx.x & 63;
    int w = threadIdx.x >> 6;
    int wm = w >> 1, wn = w & 1;
    int r0 = blockIdx.x * 64 + wm * 32;
    int c0 = blockIdx.y * 128 + wn * 64;
    int lr = l & 15, g = l >> 4;
    int lk = g * 8;

    const ushort* Af = B + (size_t)(NC_ + r0 + lr) * D_ + lk;
    const ushort* Bf = B + (size_t)(c0 + lr) * D_ + lk;

    short8_t a[2][2], b[4][2];
    #pragma unroll
    for (int rf = 0; rf < 2; ++rf)
        #pragma unroll
        for (int ks = 0; ks < 2; ++ks)
            a[rf][ks] = *(const short8_t*)(Af + rf * 16 * D_ + ks * 32);
    #pragma unroll
    for (int cf = 0; cf < 4; ++cf)
        #pragma unroll
        for (int ks = 0; ks < 2; ++ks)
            b[cf][ks] = *(const short8_t*)(Bf + cf * 16 * D_ + ks * 32);

    f32x4 acc[2][4] = {};
    #pragma unroll
    for (int ks = 0; ks < 2; ++ks)
        #pragma unroll
        for (int rf = 0; rf < 2; ++rf)
            #pragma unroll
            for (int cf = 0; cf < 4; ++cf)
                acc[rf][cf] = __builtin_amdgcn_mfma_f32_16x16x32_bf16(
                    a[rf][ks], b[cf][ks], acc[rf][cf], 0, 0, 0);

    // positive-center extraction (only col blocks covering cols < 1000)
    if (c0 < NC_) {
        #pragma unroll
        for (int rf = 0; rf < 2; ++rf)
            #pragma unroll
            for (int reg = 0; reg < 4; ++reg) {
                int row = r0 + rf * 16 + g * 4 + reg;
                int lab = labels[row];
                #pragma unroll
                for (int cf = 0; cf < 4; ++cf) {
                    int col = c0 + cf * 16 + lr;
                    if (col == lab) ws[WS_PCENT + row] = acc[rf][cf][reg];
                }
            }
    }

    // per-row (max, sumexp) over this wave's 64 cols
    __shared__ float sm[64][2], ssum[64][2];
    #pragma unroll
    for (int rf = 0; rf < 2; ++rf) {
        float sv[4][4], mx[4];
        #pragma unroll
        for (int reg = 0; reg < 4; ++reg) mx[reg] = -INFINITY;
        #pragma unroll
        for (int cf = 0; cf < 4; ++cf) {
            int col = c0 + cf * 16 + lr;
            bool valid = col < VCOLS;
            #pragma unroll
            for (int reg = 0; reg < 4; ++reg) {
                float v = valid ? acc[rf][cf][reg] * TEMP_INV : -INFINITY;
                sv[cf][reg] = v;
                mx[reg] = fmaxf(mx[reg], v);
            }
        }
        #pragma unroll
        for (int reg = 0; reg < 4; ++reg)
            #pragma unroll
            for (int msk = 1; msk < 16; msk <<= 1)
                mx[reg] = fmaxf(mx[reg], __shfl_xor(mx[reg], msk, 64));
        float se[4] = {0, 0, 0, 0};
        #pragma unroll
        for (int cf = 0; cf < 4; ++cf)
            #pragma unroll
            for (int reg = 0; reg < 4; ++reg)
                se[reg] += __expf(sv[cf][reg] - mx[reg]);
        #pragma unroll
        for (int reg = 0; reg < 4; ++reg) {
            #pragma unroll
            for (int msk = 1; msk < 16; msk <<= 1)
                se[reg] += __shfl_xor(se[reg], msk, 64);
            if (lr == 0) {
                int lrow = wm * 32 + rf * 16 + g * 4 + reg;
                sm[lrow][wn] = mx[reg];
                ssum[lrow][wn] = se[reg];
            }
        }
    }
    __syncthreads();
    int t = threadIdx.x;
    if (t < 64) {
        float m0 = sm[t][0], m1 = sm[t][1];
        float M = fmaxf(m0, m1);
        float S = ssum[t][0] * __expf(m0 - M) + ssum[t][1] * __expf(m1 - M);
        int row = blockIdx.x * 64 + t;
        ws[WS_PM + (size_t)row * PCH + blockIdx.y] = M;
        ws[WS_PS + (size_t)row * PCH + blockIdx.y] = S;
    }
}

// per-row LSE merge over PCH chunks -> contrast contribution
__global__ __launch_bounds__(256) void k_red(float* ws) {
    int w = threadIdx.x >> 6, l = threadIdx.x & 63;
    int row = blockIdx.x * 4 + w;
    const float* pm = ws + WS_PM + (size_t)row * PCH;
    const float* pv = ws + WS_PS + (size_t)row * PCH;
    float m = -INFINITY, s = 0.0f;
    for (int c = l; c < PCH; c += 64) {
        float mc = pm[c], sc = pv[c];
        float M = fmaxf(m, mc);
        s = s * __expf(m - M) + sc * __expf(mc - M);
        m = M;
    }
    #pragma unroll
    for (int msk = 1; msk < 64; msk <<= 1) {
        float om = __shfl_xor(m, msk, 64), os = __shfl_xor(s, msk, 64);
        float M = fmaxf(m, om);
        s = s * __expf(m - M) + os * __expf(om - M);
        m = M;
    }
    if (l == 0) {
        float logS = __logf(s + 1e-12f);
        float lp1 = ws[WS_PSUP + row] - m - logS;
        float lp2 = ws[WS_PCENT + row] * TEMP_INV - m - logS;
        atomicAdd(&ws[WS_ACC + A_CSUM], (lp1 + 0.02f * lp2) / (1.02f + 1e-12f));
    }
}

__global__ void k_final(const float* __restrict__ ws, float* __restrict__ out) {
    float ce = ws[WS_ACC + A_CENUM] / ws[WS_ACC + A_CEDEN];
    float contrast = -(ws[WS_ACC + A_CSUM] / (float)N_);
    float inter_mean = ws[WS_ACC + A_ISUM] / (float)(NC_ * (NC_ - 1));
    float inter_min = __uint_as_float(((const unsigned*)ws)[WS_ACC + A_IMIN]);
    float sw = ws[WS_ACC + A_SW];
    float sb = ws[WS_ACC + A_SB];
    float intra = sw / (float)N_;
    float fisher = sb / (sw + 1e-6f);
    float reg = 1.0f * intra + 0.1f / (inter_mean + 1e-6f)
              + 0.05f / (inter_min + 1e-6f) + 0.1f / (fisher + 1e-6f);
    out[0] = ce + contrast + reg;
}

extern "C" void kernel_launch(void* const* d_in, const int* in_sizes, int n_in,
                              void* d_out, int out_size, void* d_ws, size_t ws_size,
                              hipStream_t stream) {
    const float* feats        = (const float*)d_in[0];
    const float* logits       = (const float*)d_in[1];
    const int*   labels       = (const int*)d_in[2];
    const float* C            = (const float*)d_in[3];
    const float* queue        = (const float*)d_in[4];
    const float* log_prior    = (const float*)d_in[5];
    const float* class_weight = (const float*)d_in[6];
    float* ws  = (float*)d_ws;
    float* out = (float*)d_out;
    ushort* Bbf = (ushort*)(ws + WS_BBF);

    hipLaunchKernelGGL(k_init,   dim3(4),    dim3(256), 0, stream, ws);
    hipLaunchKernelGGL(k_norm_f, dim3(N_/4), dim3(256), 0, stream, feats, ws + WS_F, Bbf);
    hipLaunchKernelGGL(k_norm_c, dim3(4),    dim3(256), 0, stream, C, ws + WS_CENT, Bbf);
    hipLaunchKernelGGL(k_qbf,    dim3(1030), dim3(256), 0, stream, queue, Bbf);
    hipLaunchKernelGGL(k_stats,  dim3(64),   dim3(256), 0, stream,
                       ws + WS_F, ws + WS_CENT, labels, ws);
    hipLaunchKernelGGL(k_sb,     dim3(4),    dim3(256), 0, stream, ws + WS_CENT, ws);
    hipLaunchKernelGGL(k_gram,   dim3(256),  dim3(256), 0, stream, ws + WS_CENT, ws);
    hipLaunchKernelGGL(k_sup,    dim3(N_/4), dim3(256), 0, stream,
                       logits, labels, log_prior, class_weight, ws);
    hipLaunchKernelGGL(k_gemm,   dim3(64, 72), dim3(256), 0, stream, Bbf, labels, ws);
    hipLaunchKernelGGL(k_red,    dim3(N_/4), dim3(256), 0, stream, ws);
    hipLaunchKernelGGL(k_final,  dim3(1),    dim3(1),   0, stream, ws, out);
}